// Round 10
// baseline (987.007 us; speedup 1.0000x reference)
//
#include <hip/hip_runtime.h>
#include <math.h>

// Problem dims
#define NB 128
#define NN 36
#define S37 37            // padded stride (xseq_k)
#define S40 40            // padded stride, 16B-aligned rows (iter_k)
#define NFEAT 2048
#define NMID 517
#define KP 544            // padded K (multiple of 32) for MID-dim GEMMs
#define NHID 128
#define NOUT 1024
#define ROWS (NB*NN)      // 4608

typedef __bf16 bf16x8 __attribute__((ext_vector_type(8)));
typedef float  f32x4  __attribute__((ext_vector_type(4)));

__device__ __forceinline__ float sigf(float x){ return 1.f/(1.f+expf(-x)); }
__device__ __forceinline__ unsigned short f2bf(float x){
    unsigned u = __float_as_uint(x);
    return (unsigned short)((u + 0x7FFFu + ((u>>16)&1u)) >> 16);
}
__device__ __forceinline__ float bf2f(unsigned short b){
    return __uint_as_float(((unsigned)b) << 16);
}

// ---------------------------------------------------------------------------
// prep_all: ALL input casts/reorders/zeroing in one dispatch. Also emits
// feats_bf cols 0..4 and zero pad 517..543 (conv epilogue fills 5..516).
// ---------------------------------------------------------------------------
__global__ __launch_bounds__(256) void prep_all(
    const float* __restrict__ boxes, const float* __restrict__ att,
    const float* __restrict__ features, const float* __restrict__ conv_w,
    const float* __restrict__ wx, const float* __restrict__ wy,
    const float* __restrict__ b1, const float* __restrict__ w_ih,
    const float* __restrict__ w_hh, const float* __restrict__ b_ih,
    const float* __restrict__ b_hh,
    unsigned short* __restrict__ features_bf, unsigned short* __restrict__ convw_bf,
    unsigned short* __restrict__ wxy_bf, float* __restrict__ hxy_b,
    unsigned short* __restrict__ wih_il, unsigned short* __restrict__ whh_il,
    float* __restrict__ comb_b, unsigned short* __restrict__ h0,
    float* __restrict__ c, float* __restrict__ feats,
    unsigned short* __restrict__ feats_bf)
{
    int gtid = blockIdx.x*256 + threadIdx.x;
    int gs = gridDim.x*256;
    if (gtid < 128*64) {
        int b = gtid >> 6, t = gtid & 63;
        float mx = -1e30f;
        for (int idx = t; idx < 4*NN; idx += 64) mx = fmaxf(mx, boxes[b*4*NN + idx]);
        for (int off = 32; off > 0; off >>= 1) mx = fmaxf(mx, __shfl_down(mx, off));
        mx = __shfl(mx, 0);
        float inv = 1.f / mx;
        for (int idx = t; idx < 4*NN; idx += 64) {
            int r = idx / NN, n = idx - r*NN;
            float v = boxes[b*4*NN + idx] * inv;
            feats[(size_t)(b*NN+n)*NMID + r] = v;
            feats_bf[(size_t)(b*NN+n)*KP + r] = f2bf(v);
        }
        if (t < NN) {
            float av = att[b*NN + t];
            feats[(size_t)(b*NN+t)*NMID + 4] = av;
            feats_bf[(size_t)(b*NN+t)*KP + 4] = f2bf(av);
        }
    }
    for (int i = gtid; i < ROWS*27; i += gs) {
        int r = i / 27, cc = i - r*27;
        feats_bf[(size_t)r*KP + 517 + cc] = 0;
    }
    for (int i = gtid; i < ROWS*NFEAT; i += gs) features_bf[i] = f2bf(features[i]);
    for (int i = gtid; i < 512*NFEAT; i += gs) convw_bf[i] = f2bf(conv_w[i]);
    for (int i = gtid; i < 256*KP; i += gs) {
        int r = i / KP, k = i - r*KP;
        float v = 0.f;
        if (k < NMID) v = (r < NHID) ? wx[(size_t)r*NMID+k] : wy[(size_t)(r-NHID)*NMID+k];
        wxy_bf[i] = f2bf(v);
    }
    for (int i = gtid; i < 256; i += gs) hxy_b[i] = (i < NHID) ? b1[i] : 0.f;
    for (int i = gtid; i < 4*NOUT*KP; i += gs) {
        int row = i / KP, k = i - row*KP;
        int u = row >> 2, g = row & 3;
        wih_il[i] = (k < NMID) ? f2bf(w_ih[(size_t)(g*NOUT+u)*NMID + k]) : (unsigned short)0;
    }
    for (int i = gtid; i < 4*NOUT*NOUT; i += gs) {
        int row = i >> 10, k = i & 1023;
        int u = row >> 2, g = row & 3;
        whh_il[i] = f2bf(w_hh[(size_t)(g*NOUT+u)*NOUT + k]);
    }
    for (int i = gtid; i < 4*NOUT; i += gs) {
        int u = i >> 2, g = i & 3;
        comb_b[i] = b_ih[g*NOUT+u] + b_hh[g*NOUT+u];
    }
    for (int i = gtid; i < NB*NOUT; i += gs) { h0[i] = 0; c[i] = 0.f; }
}

// ---------------------------------------------------------------------------
// gemm_direct<NJ>: no-LDS GEMM — fragments read straight from global (L2/L3
// resident operands), ZERO barriers in the K-loop, manual next-iter fragment
// prefetch. Block tile 128 x (NJ*32); 4 waves = 2x2; wave tile 64 x (NJ*16).
// C[m,n] = sum_k A[m,k]*B[n,k] + bias[n]; writes f32 (Cf) and/or bf16 (Cb).
// ---------------------------------------------------------------------------
template<int NJ>
__global__ __launch_bounds__(256) void gemm_direct(
    const unsigned short* __restrict__ A, const unsigned short* __restrict__ B,
    const float* __restrict__ bias, float* __restrict__ Cf,
    unsigned short* __restrict__ Cb, int K, int lda, int ldb,
    int ldcf, int ldcb)
{
    int m0 = blockIdx.y * 128, n0 = blockIdx.x * (NJ * 32);
    int tid = threadIdx.x, lane = tid & 63, wave = tid >> 6;
    int wm = wave >> 1, wn = wave & 1;
    int ml = lane & 15, q = lane >> 4;
    const unsigned short* Ab = A + (size_t)(m0 + wm*64 + ml)*lda + q*8;
    const unsigned short* Bb = B + (size_t)(n0 + wn*NJ*16 + ml)*ldb + q*8;
    f32x4 acc[4][NJ];
    #pragma unroll
    for (int i = 0; i < 4; ++i)
        #pragma unroll
        for (int j = 0; j < NJ; ++j) acc[i][j] = (f32x4){0.f,0.f,0.f,0.f};
    bf16x8 afc[4], bfc[NJ];
    #pragma unroll
    for (int i = 0; i < 4; ++i) afc[i] = *(const bf16x8*)(Ab + (size_t)i*16*lda);
    #pragma unroll
    for (int j = 0; j < NJ; ++j) bfc[j] = *(const bf16x8*)(Bb + (size_t)j*16*ldb);
    for (int k0 = 0; k0 < K; k0 += 32) {
        int k1 = (k0 + 32 < K) ? (k0 + 32) : k0;
        bf16x8 afn[4], bfn[NJ];
        #pragma unroll
        for (int i = 0; i < 4; ++i) afn[i] = *(const bf16x8*)(Ab + (size_t)i*16*lda + k1);
        #pragma unroll
        for (int j = 0; j < NJ; ++j) bfn[j] = *(const bf16x8*)(Bb + (size_t)j*16*ldb + k1);
        #pragma unroll
        for (int i = 0; i < 4; ++i)
            #pragma unroll
            for (int j = 0; j < NJ; ++j)
                acc[i][j] = __builtin_amdgcn_mfma_f32_16x16x32_bf16(afc[i], bfc[j], acc[i][j], 0, 0, 0);
        #pragma unroll
        for (int i = 0; i < 4; ++i) afc[i] = afn[i];
        #pragma unroll
        for (int j = 0; j < NJ; ++j) bfc[j] = bfn[j];
    }
    int colf = lane & 15, rowq = lane >> 4;
    #pragma unroll
    for (int j = 0; j < NJ; ++j) {
        int col = n0 + wn*NJ*16 + j*16 + colf;
        float bv = bias ? bias[col] : 0.f;
        #pragma unroll
        for (int i = 0; i < 4; ++i) {
            #pragma unroll
            for (int reg = 0; reg < 4; ++reg) {
                int row = m0 + wm*64 + i*16 + rowq*4 + reg;
                float v = acc[i][j][reg] + bv;
                if (Cf) Cf[(size_t)row*ldcf + col] = v;
                if (Cb) Cb[(size_t)row*ldcb + col] = f2bf(v);
            }
        }
    }
}

// ---------------------------------------------------------------------------
// bf16 MFMA GEMM (hxy only): tile 128x64, wave tile 64x32, LDS-staged.
// ---------------------------------------------------------------------------
__global__ __launch_bounds__(256) void gemm_mfma(
    const unsigned short* __restrict__ A, const unsigned short* __restrict__ B,
    const float* __restrict__ bias, void* __restrict__ Cp,
    int K, int lda, int ldb, int ldc, int obf)
{
    __shared__ __align__(16) char As[8192];
    __shared__ __align__(16) char Bs[4096];
    int m0 = blockIdx.y * 128, n0 = blockIdx.x * 64;
    int tid = threadIdx.x;
    int lane = tid & 63, wave = tid >> 6;
    int wm = wave >> 1, wn = wave & 1;
    f32x4 acc[4][2];
    #pragma unroll
    for (int i = 0; i < 4; ++i)
        #pragma unroll
        for (int j = 0; j < 2; ++j) acc[i][j] = (f32x4){0.f,0.f,0.f,0.f};

    for (int k0 = 0; k0 < K; k0 += 32) {
        #pragma unroll
        for (int cc = tid; cc < 512; cc += 256) {
            int r = cc >> 2, q = cc & 3;
            uint4 v = *(const uint4*)(A + (size_t)(m0+r)*lda + k0 + q*8);
            *(uint4*)(As + ((r>>4)<<10) + (q<<8) + ((r&15)<<4)) = v;
        }
        {
            int r = tid >> 2, q = tid & 3;
            uint4 v = *(const uint4*)(B + (size_t)(n0+r)*ldb + k0 + q*8);
            *(uint4*)(Bs + ((r>>4)<<10) + (q<<8) + ((r&15)<<4)) = v;
        }
        __syncthreads();
        bf16x8 af[4], bfr[2];
        #pragma unroll
        for (int i = 0; i < 4; ++i) af[i]  = *(bf16x8*)(As + ((wm*4+i)<<10) + (lane<<4));
        #pragma unroll
        for (int j = 0; j < 2; ++j) bfr[j] = *(bf16x8*)(Bs + ((wn*2+j)<<10) + (lane<<4));
        #pragma unroll
        for (int i = 0; i < 4; ++i)
            #pragma unroll
            for (int j = 0; j < 2; ++j)
                acc[i][j] = __builtin_amdgcn_mfma_f32_16x16x32_bf16(af[i], bfr[j], acc[i][j], 0, 0, 0);
        __syncthreads();
    }
    int colf = lane & 15, rowq = lane >> 4;
    #pragma unroll
    for (int j = 0; j < 2; ++j) {
        int col = n0 + (wn*2+j)*16 + colf;
        float bv = bias ? bias[col] : 0.f;
        #pragma unroll
        for (int i = 0; i < 4; ++i) {
            #pragma unroll
            for (int reg = 0; reg < 4; ++reg) {
                int row = m0 + (wm*4+i)*16 + rowq*4 + reg;
                float v = acc[i][j][reg] + bv;
                if (obf) ((unsigned short*)Cp)[(size_t)row*ldc + col] = f2bf(v);
                else     ((float*)Cp)[(size_t)row*ldc + col] = v;
            }
        }
    }
}

// ---------------------------------------------------------------------------
// out_k: grid (128,4). rows i0..i0+8 of out[b][i][j] = w2.relu(hx_i+hy_j)
// ---------------------------------------------------------------------------
__global__ __launch_bounds__(256) void out_k(
    const float* __restrict__ hxy, const float* __restrict__ w2,
    float* __restrict__ out_g)
{
    __shared__ float s_hx[9*129], s_hy[NN*129], s_w2[NHID];
    int b = blockIdx.x, i0 = blockIdx.y * 9, tid = threadIdx.x;
    for (int i = tid; i < 9*NHID; i += 256) {
        int n = i >> 7, h = i & 127;
        s_hx[n*129+h] = hxy[(size_t)(b*NN+i0+n)*256 + h];
    }
    for (int i = tid; i < NN*NHID; i += 256) {
        int n = i >> 7, h = i & 127;
        s_hy[n*129+h] = hxy[(size_t)(b*NN+n)*256 + 128 + h];
    }
    if (tid < NHID) s_w2[tid] = w2[tid];
    __syncthreads();
    for (int idx = tid; idx < 9*NN; idx += 256) {
        int il = idx / NN, j = idx - il*NN;
        const float* px = &s_hx[il*129];
        const float* py = &s_hy[j*129];
        float s = 0.f;
        #pragma unroll 8
        for (int h = 0; h < NHID; ++h) s += s_w2[h] * fmaxf(px[h] + py[h], 0.f);
        out_g[(size_t)b*NN*NN + (i0+il)*NN + j] = s;
    }
}

// ---------------------------------------------------------------------------
// iter_k: grid 128. C = out - out^T, 3 assignment iters, final A row-softmax
// pre-scaled by sigmoid(att) -> A_g.
// ---------------------------------------------------------------------------
__global__ __launch_bounds__(256) void iter_k(
    const float* __restrict__ out_g, const float* __restrict__ att,
    const float* __restrict__ lr, float* __restrict__ A_g)
{
    __shared__ __align__(16) float s_out[NN*S40], s_C[NN*S40], s_logits[NN*S40], s_P[NN*S40];
    __shared__ float s_sg[NN];
    int b = blockIdx.x, tid = threadIdx.x;
    for (int idx = tid; idx < NN*NN; idx += 256) {
        int i = idx / NN, j = idx - i*NN;
        s_out[i*S40+j] = out_g[(size_t)b*NN*NN + idx];
        s_logits[i*S40+j] = 0.f;
    }
    if (tid < NN) s_sg[tid] = sigf(att[b*NN + tid]);
    float lr_abs = fabsf(lr[0]);
    __syncthreads();
    for (int idx = tid; idx < NN*NN; idx += 256) {
        int i = idx / NN, j = idx - i*NN;
        s_C[i*S40+j] = s_out[i*S40+j] - s_out[j*S40+i];
    }
    __syncthreads();
    for (int it = 0; it < 3; ++it) {
        if (tid < NN) {
            int i = tid;
            float mx = -1e30f;
            for (int l = 0; l < NN; ++l) mx = fmaxf(mx, s_logits[i*S40+l]);
            float sum = 0.f;
            for (int l = 0; l < NN; ++l) { float e = expf(s_logits[i*S40+l]-mx); s_P[i*S40+l] = e; sum += e; }
            float inv = 1.f/sum;
            for (int l = 0; l < NN; ++l) s_P[i*S40+l] *= inv;
        }
        __syncthreads();
        if (tid < NN) {
            int l = tid;
            float S = 0.f;
            for (int i = 0; i < NN; ++i) S += s_P[i*S40+l];
            float cum = 0.f;
            for (int i = 0; i < NN; ++i) {
                float p = s_P[i*S40+l];
                cum += p;
                s_P[i*S40+l] = S - 2.f*cum + p;
            }
        }
        __syncthreads();
        for (int idx = tid; idx < NN*NN; idx += 256) {
            int i = idx / NN, j = idx - i*NN;
            const f32x4* Pp = (const f32x4*)&s_P[i*S40];
            const f32x4* Cc = (const f32x4*)&s_C[j*S40];
            float g = 0.f;
            #pragma unroll
            for (int qq = 0; qq < 9; ++qq) {
                f32x4 a = Pp[qq], bb = Cc[qq];
                g += a[0]*bb[0] + a[1]*bb[1] + a[2]*bb[2] + a[3]*bb[3];
            }
            s_logits[i*S40+j] -= lr_abs * g;
        }
        __syncthreads();
    }
    if (tid < NN) {
        int i = tid;
        float mx = -1e30f;
        for (int l = 0; l < NN; ++l) mx = fmaxf(mx, s_logits[i*S40+l]);
        float sum = 0.f;
        for (int l = 0; l < NN; ++l) { float e = expf(s_logits[i*S40+l]-mx); s_P[i*S40+l] = e; sum += e; }
        float inv = 1.f/sum;
        for (int l = 0; l < NN; ++l)
            A_g[(size_t)b*NN*NN + i*NN + l] = s_P[i*S40+l] * inv * s_sg[l];
    }
}

// ---------------------------------------------------------------------------
// xseq_k: grid (128,2). xseq[i][b][c] = sum_l A[b][i][l]*feats[b][l][c], bf16.
// ---------------------------------------------------------------------------
__global__ __launch_bounds__(256) void xseq_k(
    const float* __restrict__ feats, const float* __restrict__ A_g,
    unsigned short* __restrict__ xseq)
{
    __shared__ float s_P[NN*S37];
    int b = blockIdx.x, half = blockIdx.y, tid = threadIdx.x;
    for (int idx = tid; idx < NN*NN; idx += 256) {
        int i = idx / NN, l = idx - i*NN;
        s_P[i*S37+l] = A_g[(size_t)b*NN*NN + idx];
    }
    __syncthreads();
    const float* fb = feats + (size_t)b*NN*NMID;
    int ncols = (half == 0 && tid < 32) ? 2 : 1;
    #pragma unroll
    for (int rep = 0; rep < 2; ++rep) {
        if (rep >= ncols) break;
        int c = (rep == 0) ? half*256 + tid : 512 + tid;
        float colv[NN];
        #pragma unroll
        for (int l = 0; l < NN; ++l) colv[l] = (c < NMID) ? fb[l*NMID + c] : 0.f;
        #pragma unroll 4
        for (int i = 0; i < NN; ++i) {
            float s = 0.f;
            #pragma unroll
            for (int l = 0; l < NN; ++l) s += s_P[i*S37+l] * colv[l];
            xseq[((size_t)i*NB + b)*KP + c] = f2bf(s);
        }
    }
}

// ---------------------------------------------------------------------------
// LSTM step v8: per-step launch (persistent+grid-barrier measured 20us/step
// across two barrier designs — abandoned). Grid 512 = bt(4 x 32batch)*128 +
// ct(128 x 32col). NO LDS staging: A (=h) and B (=whh) MFMA fragments read
// DIRECTLY from global — whh slice is L2-resident across launches (per-XCD
// working set ~1.3MB: blockIdx%8 pins same-ct blocks to one XCD). Zero
// barriers in the K-loop. Wave tile 16b x 16c, 1 MFMA/iter, 32 iters.
// Cols unit-interleaved (col = u*4+g); xw has b_ih+b_hh folded.
// ---------------------------------------------------------------------------
__global__ __launch_bounds__(256) void lstm_step(
    const unsigned short* __restrict__ h_in, const unsigned short* __restrict__ whh,
    const unsigned short* __restrict__ xw_t, float* __restrict__ c,
    unsigned short* __restrict__ h_out, float* __restrict__ cout)
{
    __shared__ __align__(16) float gates[32][36];
    int tid = threadIdx.x, lane = tid & 63, wave = tid >> 6;
    int bt = blockIdx.x >> 7, ct = blockIdx.x & 127;
    int m0 = bt * 32, n0 = ct * 32;
    int wm = wave >> 1, wn = wave & 1;
    int ml = lane & 15, q = lane >> 4;
    const unsigned short* Ab = h_in + (size_t)(m0 + wm*16 + ml)*NOUT + q*8;
    const unsigned short* Bb = whh  + (size_t)(n0 + wn*16 + ml)*NOUT + q*8;
    f32x4 acc = (f32x4){0.f,0.f,0.f,0.f};
    #pragma unroll 8
    for (int it = 0; it < 32; ++it) {
        bf16x8 a = *(const bf16x8*)(Ab + it*32);
        bf16x8 b = *(const bf16x8*)(Bb + it*32);
        acc = __builtin_amdgcn_mfma_f32_16x16x32_bf16(a, b, acc, 0, 0, 0);
    }
    #pragma unroll
    for (int reg = 0; reg < 4; ++reg)
        gates[wm*16 + q*4 + reg][wn*16 + ml] = acc[reg];
    __syncthreads();
    // epilogue: 32 batches x 8 units = 256 pairs, 1/thread
    {
        int ul = tid & 7, bl = tid >> 3;
        int b = m0 + bl, u = ct*8 + ul;
        float4 gl = *(const float4*)&gates[bl][ul*4];
        uint2 xw2 = *(const uint2*)(xw_t + (size_t)b*4*NOUT + n0 + ul*4);
        float g0 = gl.x + bf2f((unsigned short)(xw2.x & 0xffffu));
        float g1 = gl.y + bf2f((unsigned short)(xw2.x >> 16));
        float g2 = gl.z + bf2f((unsigned short)(xw2.y & 0xffffu));
        float g3 = gl.w + bf2f((unsigned short)(xw2.y >> 16));
        float ig = sigf(g0), fg = sigf(g1), gg = tanhf(g2), og = sigf(g3);
        size_t o = (size_t)b*NOUT + u;
        float cc = fg*c[o] + ig*gg;
        c[o] = cc;
        if (cout) cout[o] = cc;
        else      h_out[o] = f2bf(og*tanhf(cc));
    }
}

// ---------------------------------------------------------------------------
extern "C" void kernel_launch(void* const* d_in, const int* in_sizes, int n_in,
                              void* d_out, int out_size, void* d_ws, size_t ws_size,
                              hipStream_t stream) {
    (void)in_sizes; (void)n_in; (void)out_size; (void)ws_size;
    const float* boxes     = (const float*)d_in[0];
    const float* attention = (const float*)d_in[1];
    const float* features  = (const float*)d_in[2];
    const float* conv_w    = (const float*)d_in[3];
    const float* conv_b    = (const float*)d_in[4];
    const float* skew_wx   = (const float*)d_in[5];
    const float* skew_wy   = (const float*)d_in[6];
    const float* skew_b1   = (const float*)d_in[7];
    const float* skew_w2   = (const float*)d_in[8];
    // d_in[9] = skew_b2: cancels in C = out - out^T
    const float* w_ih      = (const float*)d_in[10];
    const float* w_hh      = (const float*)d_in[11];
    const float* b_ih      = (const float*)d_in[12];
    const float* b_hh      = (const float*)d_in[13];
    const float* lr        = (const float*)d_in[14];

    // workspace layout (bytes, 256-aligned)
    char* ws = (char*)d_ws;
    unsigned short* xw_bf    = (unsigned short*)(ws);             // 4608x4096 bf16 37,748,736
    unsigned short* features_bf = (unsigned short*)(ws + 37748736); // 18,874,368
    unsigned short* convw_bf = (unsigned short*)(ws + 56623104);  //  2,097,152
    float*          feats    = (float*)(ws + 58720256);           //  9,529,344
    float*          hxy      = (float*)(ws + 68249600);           //  4,718,592
    unsigned short* feats_bf = (unsigned short*)(ws + 72968192);  //  5,013,504
    unsigned short* xseq_bf  = (unsigned short*)(ws + 77981696);  //  5,013,504
    unsigned short* wih_il   = (unsigned short*)(ws + 82995200);  //  4,456,448
    unsigned short* whh_il   = (unsigned short*)(ws + 87451648);  //  8,388,608
    unsigned short* wxy_bf   = (unsigned short*)(ws + 95840256);  //    278,528
    float*          comb_b   = (float*)(ws + 96118784);           //     16,384
    float*          hxy_b    = (float*)(ws + 96135168);           //      1,024
    unsigned short* h0       = (unsigned short*)(ws + 96136192);  //    262,144
    unsigned short* h1       = (unsigned short*)(ws + 96398336);  //    262,144
    float*          out_g    = (float*)(ws + 96660480);           //    663,552
    float*          A_g      = (float*)(ws + 97324032);           //    663,552
    float*          cst      = (float*)(ws + 97987584);           //    524,288

    prep_all<<<2048, 256, 0, stream>>>(boxes, attention, features, conv_w,
                                       skew_wx, skew_wy, skew_b1, w_ih, w_hh,
                                       b_ih, b_hh, features_bf, convw_bf,
                                       wxy_bf, hxy_b, wih_il, whh_il, comb_b,
                                       h0, cst, feats, feats_bf);
    // conv (no-LDS direct): feats[:,5:517] f32 AND feats_bf[:,5:517] bf16
    gemm_direct<2><<<dim3(8, 36), 256, 0, stream>>>(
        features_bf, convw_bf, conv_b, feats + 5, feats_bf + 5,
        NFEAT, NFEAT, NFEAT, NMID, KP);
    // hxy = feats . [wx;wy]^T + [b1;0]
    gemm_mfma<<<dim3(4, 36), 256, 0, stream>>>(feats_bf, wxy_bf, hxy_b,
                                               (void*)hxy, KP, KP, KP, 256, 0);
    // assignment pipeline
    out_k<<<dim3(NB, 4), 256, 0, stream>>>(hxy, skew_w2, out_g);
    iter_k<<<NB, 256, 0, stream>>>(out_g, attention, lr, A_g);
    xseq_k<<<dim3(NB, 2), 256, 0, stream>>>(feats, A_g, xseq_bf);
    // xw = xseq . w_ih_il^T + (b_ih+b_hh) -> bf16 (no-LDS direct)
    gemm_direct<4><<<dim3(32, 36), 256, 0, stream>>>(
        xseq_bf, wih_il, comb_b, nullptr, xw_bf,
        KP, KP, KP, 0, 4*NOUT);
    unsigned short* hbuf[2] = {h0, h1};
    for (int t = 0; t < NN; ++t) {
        float* co = (t == NN-1) ? (float*)d_out : nullptr;
        lstm_step<<<512, 256, 0, stream>>>(hbuf[t & 1], whh_il,
                                           xw_bf + (size_t)t*NB*4*NOUT, cst,
                                           hbuf[(t+1) & 1], co);
    }
}

// Round 11
// 795.092 us; speedup vs baseline: 1.2414x; 1.2414x over previous
//
#include <hip/hip_runtime.h>
#include <math.h>

// Problem dims
#define NB 128
#define NN 36
#define S37 37            // padded stride (xseq_k)
#define S40 40            // padded stride, 16B-aligned rows (iter_k)
#define NFEAT 2048
#define NMID 517
#define KP 544            // padded K (multiple of 32) for MID-dim GEMMs
#define NHID 128
#define NOUT 1024
#define ROWS (NB*NN)      // 4608

typedef __bf16 bf16x8 __attribute__((ext_vector_type(8)));
typedef float  f32x4  __attribute__((ext_vector_type(4)));

__device__ __forceinline__ float sigf(float x){ return 1.f/(1.f+expf(-x)); }
__device__ __forceinline__ unsigned short f2bf(float x){
    unsigned u = __float_as_uint(x);
    return (unsigned short)((u + 0x7FFFu + ((u>>16)&1u)) >> 16);
}
__device__ __forceinline__ float bf2f(unsigned short b){
    return __uint_as_float(((unsigned)b) << 16);
}

// ---------------------------------------------------------------------------
// prep_all: ALL input casts/reorders/zeroing in one dispatch.
// ---------------------------------------------------------------------------
__global__ __launch_bounds__(256) void prep_all(
    const float* __restrict__ boxes, const float* __restrict__ att,
    const float* __restrict__ features, const float* __restrict__ conv_w,
    const float* __restrict__ wx, const float* __restrict__ wy,
    const float* __restrict__ b1, const float* __restrict__ w_ih,
    const float* __restrict__ w_hh, const float* __restrict__ b_ih,
    const float* __restrict__ b_hh,
    unsigned short* __restrict__ features_bf, unsigned short* __restrict__ convw_bf,
    unsigned short* __restrict__ wxy_bf, float* __restrict__ hxy_b,
    unsigned short* __restrict__ wih_il, unsigned short* __restrict__ whh_il,
    float* __restrict__ comb_b, unsigned short* __restrict__ h0,
    unsigned* __restrict__ bar, float* __restrict__ feats)
{
    int gtid = blockIdx.x*256 + threadIdx.x;
    int gs = gridDim.x*256;
    if (gtid < 128*64) {
        int b = gtid >> 6, t = gtid & 63;
        float mx = -1e30f;
        for (int idx = t; idx < 4*NN; idx += 64) mx = fmaxf(mx, boxes[b*4*NN + idx]);
        for (int off = 32; off > 0; off >>= 1) mx = fmaxf(mx, __shfl_down(mx, off));
        mx = __shfl(mx, 0);
        float inv = 1.f / mx;
        for (int idx = t; idx < 4*NN; idx += 64) {
            int r = idx / NN, n = idx - r*NN;
            feats[(size_t)(b*NN+n)*NMID + r] = boxes[b*4*NN + idx] * inv;
        }
        if (t < NN) feats[(size_t)(b*NN+t)*NMID + 4] = att[b*NN + t];
    }
    for (int i = gtid; i < ROWS*NFEAT; i += gs) features_bf[i] = f2bf(features[i]);
    for (int i = gtid; i < 512*NFEAT; i += gs) convw_bf[i] = f2bf(conv_w[i]);
    for (int i = gtid; i < 256*KP; i += gs) {
        int r = i / KP, k = i - r*KP;
        float v = 0.f;
        if (k < NMID) v = (r < NHID) ? wx[(size_t)r*NMID+k] : wy[(size_t)(r-NHID)*NMID+k];
        wxy_bf[i] = f2bf(v);
    }
    for (int i = gtid; i < 256; i += gs) hxy_b[i] = (i < NHID) ? b1[i] : 0.f;
    for (int i = gtid; i < 4*NOUT*KP; i += gs) {
        int row = i / KP, k = i - row*KP;
        int u = row >> 2, g = row & 3;
        wih_il[i] = (k < NMID) ? f2bf(w_ih[(size_t)(g*NOUT+u)*NMID + k]) : (unsigned short)0;
    }
    for (int i = gtid; i < 4*NOUT*NOUT; i += gs) {
        int row = i >> 10, k = i & 1023;
        int u = row >> 2, g = row & 3;
        whh_il[i] = f2bf(w_hh[(size_t)(g*NOUT+u)*NOUT + k]);
    }
    for (int i = gtid; i < 4*NOUT; i += gs) {
        int u = i >> 2, g = i & 3;
        comb_b[i] = b_ih[g*NOUT+u] + b_hh[g*NOUT+u];
    }
    for (int i = gtid; i < NB*NOUT; i += gs) h0[i] = 0;
    for (int i = gtid; i < 4096 + 16; i += gs) bar[i] = 0;   // domain flag array
}

// ---------------------------------------------------------------------------
// gemm128: C[m,n] = sum_k A[m,k]*B[n,k] (+ bias). Block tile 128x128,
// 4 waves = 2x2, wave tile 64x64. XOR-swizzled LDS. Optional split-K.
// (Round-7-proven: conv 49us, xw 49us. Round-10's no-LDS variant regressed
// to 92us — A-reuse must go through LDS when A doesn't fit L2.)
// ---------------------------------------------------------------------------
__global__ __launch_bounds__(256) void gemm128(
    const unsigned short* __restrict__ A, const unsigned short* __restrict__ B,
    const float* __restrict__ bias, void* __restrict__ Cp,
    int Ksl, int lda, int ldb, int ldc, int obf, long long pstride)
{
    __shared__ __align__(16) char As[16384];
    __shared__ __align__(16) char Bs[16384];
    int m0 = blockIdx.y * 128, n0 = blockIdx.x * 128;
    int kbeg = blockIdx.z * Ksl;
    int tid = threadIdx.x;
    int lane = tid & 63, wave = tid >> 6;
    int wm = wave >> 1, wn = wave & 1;
    int sw = ((lane>>4)<<8) + (((lane&15) ^ ((lane>>4)<<2))<<4);
    f32x4 acc[4][4];
    #pragma unroll
    for (int i = 0; i < 4; ++i)
        #pragma unroll
        for (int j = 0; j < 4; ++j) acc[i][j] = (f32x4){0.f,0.f,0.f,0.f};

    for (int k0 = 0; k0 < Ksl; k0 += 32) {
        #pragma unroll
        for (int p = 0; p < 2; ++p) {
            int cc = p*256 + tid;
            int r = cc >> 2, q = cc & 3;
            int sa = ((r>>4)<<10) + (q<<8) + ((((r&15) ^ (q<<2)))<<4);
            uint4 va = *(const uint4*)(A + (size_t)(m0+r)*lda + kbeg + k0 + q*8);
            *(uint4*)(As + sa) = va;
            uint4 vb = *(const uint4*)(B + (size_t)(n0+r)*ldb + kbeg + k0 + q*8);
            *(uint4*)(Bs + sa) = vb;
        }
        __syncthreads();
        bf16x8 af[4], bfr[4];
        #pragma unroll
        for (int i = 0; i < 4; ++i) af[i]  = *(bf16x8*)(As + ((wm*4+i)<<10) + sw);
        #pragma unroll
        for (int j = 0; j < 4; ++j) bfr[j] = *(bf16x8*)(Bs + ((wn*4+j)<<10) + sw);
        #pragma unroll
        for (int i = 0; i < 4; ++i)
            #pragma unroll
            for (int j = 0; j < 4; ++j)
                acc[i][j] = __builtin_amdgcn_mfma_f32_16x16x32_bf16(af[i], bfr[j], acc[i][j], 0, 0, 0);
        __syncthreads();
    }
    int colf = lane & 15, rowq = lane >> 4;
    #pragma unroll
    for (int j = 0; j < 4; ++j) {
        int col = n0 + (wn*4+j)*16 + colf;
        float bv = bias ? bias[col] : 0.f;
        #pragma unroll
        for (int i = 0; i < 4; ++i) {
            #pragma unroll
            for (int reg = 0; reg < 4; ++reg) {
                int row = m0 + (wm*4+i)*16 + rowq*4 + reg;
                float v = acc[i][j][reg] + bv;
                if (obf) ((unsigned short*)Cp)[(size_t)row*ldc + col] = f2bf(v);
                else ((float*)Cp + (size_t)blockIdx.z*pstride)[(size_t)row*ldc + col] = v;
            }
        }
    }
}

// ---------------------------------------------------------------------------
// conv_reduce: feats[:,5:] = sum_z part[z] + conv_b; emits full padded bf16.
// ---------------------------------------------------------------------------
__global__ __launch_bounds__(256) void conv_reduce(
    const float* __restrict__ part, const float* __restrict__ bias,
    float* __restrict__ feats, unsigned short* __restrict__ feats_bf)
{
    int gtid = blockIdx.x*256 + threadIdx.x;
    int gs = gridDim.x*256;
    const size_t PS = (size_t)ROWS * 512;
    for (int i = gtid; i < ROWS*512; i += gs) {
        int r = i >> 9, cc = i & 511;
        float s = part[i] + part[PS+i] + part[2*PS+i] + part[3*PS+i] + bias[cc];
        feats[(size_t)r*NMID + 5 + cc] = s;
        feats_bf[(size_t)r*KP + 5 + cc] = f2bf(s);
    }
    for (int i = gtid; i < ROWS*5; i += gs) {
        int r = i / 5, cc = i - r*5;
        feats_bf[(size_t)r*KP + cc] = f2bf(feats[(size_t)r*NMID + cc]);
    }
    for (int i = gtid; i < ROWS*27; i += gs) {
        int r = i / 27, cc = i - r*27;
        feats_bf[(size_t)r*KP + 517 + cc] = 0;
    }
}

// ---------------------------------------------------------------------------
// bf16 MFMA GEMM (hxy only): tile 128x64, wave tile 64x32, LDS-staged.
// ---------------------------------------------------------------------------
__global__ __launch_bounds__(256) void gemm_mfma(
    const unsigned short* __restrict__ A, const unsigned short* __restrict__ B,
    const float* __restrict__ bias, void* __restrict__ Cp,
    int K, int lda, int ldb, int ldc, int obf)
{
    __shared__ __align__(16) char As[8192];
    __shared__ __align__(16) char Bs[4096];
    int m0 = blockIdx.y * 128, n0 = blockIdx.x * 64;
    int tid = threadIdx.x;
    int lane = tid & 63, wave = tid >> 6;
    int wm = wave >> 1, wn = wave & 1;
    f32x4 acc[4][2];
    #pragma unroll
    for (int i = 0; i < 4; ++i)
        #pragma unroll
        for (int j = 0; j < 2; ++j) acc[i][j] = (f32x4){0.f,0.f,0.f,0.f};

    for (int k0 = 0; k0 < K; k0 += 32) {
        #pragma unroll
        for (int cc = tid; cc < 512; cc += 256) {
            int r = cc >> 2, q = cc & 3;
            uint4 v = *(const uint4*)(A + (size_t)(m0+r)*lda + k0 + q*8);
            *(uint4*)(As + ((r>>4)<<10) + (q<<8) + ((r&15)<<4)) = v;
        }
        {
            int r = tid >> 2, q = tid & 3;
            uint4 v = *(const uint4*)(B + (size_t)(n0+r)*ldb + k0 + q*8);
            *(uint4*)(Bs + ((r>>4)<<10) + (q<<8) + ((r&15)<<4)) = v;
        }
        __syncthreads();
        bf16x8 af[4], bfr[2];
        #pragma unroll
        for (int i = 0; i < 4; ++i) af[i]  = *(bf16x8*)(As + ((wm*4+i)<<10) + (lane<<4));
        #pragma unroll
        for (int j = 0; j < 2; ++j) bfr[j] = *(bf16x8*)(Bs + ((wn*2+j)<<10) + (lane<<4));
        #pragma unroll
        for (int i = 0; i < 4; ++i)
            #pragma unroll
            for (int j = 0; j < 2; ++j)
                acc[i][j] = __builtin_amdgcn_mfma_f32_16x16x32_bf16(af[i], bfr[j], acc[i][j], 0, 0, 0);
        __syncthreads();
    }
    int colf = lane & 15, rowq = lane >> 4;
    #pragma unroll
    for (int j = 0; j < 2; ++j) {
        int col = n0 + (wn*2+j)*16 + colf;
        float bv = bias ? bias[col] : 0.f;
        #pragma unroll
        for (int i = 0; i < 4; ++i) {
            #pragma unroll
            for (int reg = 0; reg < 4; ++reg) {
                int row = m0 + (wm*4+i)*16 + rowq*4 + reg;
                float v = acc[i][j][reg] + bv;
                if (obf) ((unsigned short*)Cp)[(size_t)row*ldc + col] = f2bf(v);
                else     ((float*)Cp)[(size_t)row*ldc + col] = v;
            }
        }
    }
}

// ---------------------------------------------------------------------------
// out_k: grid (128,4). rows i0..i0+8 of out[b][i][j] = w2.relu(hx_i+hy_j)
// ---------------------------------------------------------------------------
__global__ __launch_bounds__(256) void out_k(
    const float* __restrict__ hxy, const float* __restrict__ w2,
    float* __restrict__ out_g)
{
    __shared__ float s_hx[9*129], s_hy[NN*129], s_w2[NHID];
    int b = blockIdx.x, i0 = blockIdx.y * 9, tid = threadIdx.x;
    for (int i = tid; i < 9*NHID; i += 256) {
        int n = i >> 7, h = i & 127;
        s_hx[n*129+h] = hxy[(size_t)(b*NN+i0+n)*256 + h];
    }
    for (int i = tid; i < NN*NHID; i += 256) {
        int n = i >> 7, h = i & 127;
        s_hy[n*129+h] = hxy[(size_t)(b*NN+n)*256 + 128 + h];
    }
    if (tid < NHID) s_w2[tid] = w2[tid];
    __syncthreads();
    for (int idx = tid; idx < 9*NN; idx += 256) {
        int il = idx / NN, j = idx - il*NN;
        const float* px = &s_hx[il*129];
        const float* py = &s_hy[j*129];
        float s = 0.f;
        #pragma unroll 8
        for (int h = 0; h < NHID; ++h) s += s_w2[h] * fmaxf(px[h] + py[h], 0.f);
        out_g[(size_t)b*NN*NN + (i0+il)*NN + j] = s;
    }
}

// ---------------------------------------------------------------------------
// iter_k: grid 128. C = out - out^T, 3 assignment iters, final A row-softmax
// pre-scaled by sigmoid(att) -> A_g.
// ---------------------------------------------------------------------------
__global__ __launch_bounds__(256) void iter_k(
    const float* __restrict__ out_g, const float* __restrict__ att,
    const float* __restrict__ lr, float* __restrict__ A_g)
{
    __shared__ __align__(16) float s_out[NN*S40], s_C[NN*S40], s_logits[NN*S40], s_P[NN*S40];
    __shared__ float s_sg[NN];
    int b = blockIdx.x, tid = threadIdx.x;
    for (int idx = tid; idx < NN*NN; idx += 256) {
        int i = idx / NN, j = idx - i*NN;
        s_out[i*S40+j] = out_g[(size_t)b*NN*NN + idx];
        s_logits[i*S40+j] = 0.f;
    }
    if (tid < NN) s_sg[tid] = sigf(att[b*NN + tid]);
    float lr_abs = fabsf(lr[0]);
    __syncthreads();
    for (int idx = tid; idx < NN*NN; idx += 256) {
        int i = idx / NN, j = idx - i*NN;
        s_C[i*S40+j] = s_out[i*S40+j] - s_out[j*S40+i];
    }
    __syncthreads();
    for (int it = 0; it < 3; ++it) {
        if (tid < NN) {
            int i = tid;
            float mx = -1e30f;
            for (int l = 0; l < NN; ++l) mx = fmaxf(mx, s_logits[i*S40+l]);
            float sum = 0.f;
            for (int l = 0; l < NN; ++l) { float e = expf(s_logits[i*S40+l]-mx); s_P[i*S40+l] = e; sum += e; }
            float inv = 1.f/sum;
            for (int l = 0; l < NN; ++l) s_P[i*S40+l] *= inv;
        }
        __syncthreads();
        if (tid < NN) {
            int l = tid;
            float S = 0.f;
            for (int i = 0; i < NN; ++i) S += s_P[i*S40+l];
            float cum = 0.f;
            for (int i = 0; i < NN; ++i) {
                float p = s_P[i*S40+l];
                cum += p;
                s_P[i*S40+l] = S - 2.f*cum + p;
            }
        }
        __syncthreads();
        for (int idx = tid; idx < NN*NN; idx += 256) {
            int i = idx / NN, j = idx - i*NN;
            const f32x4* Pp = (const f32x4*)&s_P[i*S40];
            const f32x4* Cc = (const f32x4*)&s_C[j*S40];
            float g = 0.f;
            #pragma unroll
            for (int qq = 0; qq < 9; ++qq) {
                f32x4 a = Pp[qq], bb = Cc[qq];
                g += a[0]*bb[0] + a[1]*bb[1] + a[2]*bb[2] + a[3]*bb[3];
            }
            s_logits[i*S40+j] -= lr_abs * g;
        }
        __syncthreads();
    }
    if (tid < NN) {
        int i = tid;
        float mx = -1e30f;
        for (int l = 0; l < NN; ++l) mx = fmaxf(mx, s_logits[i*S40+l]);
        float sum = 0.f;
        for (int l = 0; l < NN; ++l) { float e = expf(s_logits[i*S40+l]-mx); s_P[i*S40+l] = e; sum += e; }
        float inv = 1.f/sum;
        for (int l = 0; l < NN; ++l)
            A_g[(size_t)b*NN*NN + i*NN + l] = s_P[i*S40+l] * inv * s_sg[l];
    }
}

// ---------------------------------------------------------------------------
// xseq_k: grid (128,2). xseq[i][b][c] = sum_l A[b][i][l]*feats[b][l][c], bf16.
// ---------------------------------------------------------------------------
__global__ __launch_bounds__(256) void xseq_k(
    const float* __restrict__ feats, const float* __restrict__ A_g,
    unsigned short* __restrict__ xseq)
{
    __shared__ float s_P[NN*S37];
    int b = blockIdx.x, half = blockIdx.y, tid = threadIdx.x;
    for (int idx = tid; idx < NN*NN; idx += 256) {
        int i = idx / NN, l = idx - i*NN;
        s_P[i*S37+l] = A_g[(size_t)b*NN*NN + idx];
    }
    __syncthreads();
    const float* fb = feats + (size_t)b*NN*NMID;
    int ncols = (half == 0 && tid < 32) ? 2 : 1;
    #pragma unroll
    for (int rep = 0; rep < 2; ++rep) {
        if (rep >= ncols) break;
        int c = (rep == 0) ? half*256 + tid : 512 + tid;
        float colv[NN];
        #pragma unroll
        for (int l = 0; l < NN; ++l) colv[l] = (c < NMID) ? fb[l*NMID + c] : 0.f;
        #pragma unroll 4
        for (int i = 0; i < NN; ++i) {
            float s = 0.f;
            #pragma unroll
            for (int l = 0; l < NN; ++l) s += s_P[i*S37+l] * colv[l];
            xseq[((size_t)i*NB + b)*KP + c] = f2bf(s);
        }
    }
}

// ---------------------------------------------------------------------------
// lstm_domains: persistent LSTM with DOMAIN-LOCAL barriers. Key insight: the
// recurrence couples blocks only through h of the SAME batches — so split
// into 4 independent sync domains of 64 blocks (32 batches each). Block
// (g, j) owns batches [32g,32g+32) x gate-cols [64j,64j+64) (= units
// [16j,16j+16)). whh slice (64 cols x 1024 K = 128KB) lives in LDS for all
// 36 steps; c in registers. Barrier per domain = 64-wide flag array using
// round-9's verified release/poll/acquire recipe (correct for any
// block->XCD placement; G16). Grid 256 = 1 block/CU, 137KB LDS: co-resident.
// ---------------------------------------------------------------------------
__global__ __launch_bounds__(256) void lstm_domains(
    const unsigned short* __restrict__ whh, const unsigned short* __restrict__ xw,
    unsigned short* __restrict__ h0, unsigned short* __restrict__ h1,
    float* __restrict__ cout, unsigned* __restrict__ bar)
{
    __shared__ __align__(16) char Bls[131072];     // [kc 0..127][n' 0..63][16B]
    __shared__ __align__(16) float gates[32][68];
    int tid = threadIdx.x, lane = tid & 63, wave = tid >> 6;
    int g = blockIdx.x >> 6, j = blockIdx.x & 63;  // domain, col-block
    int m0 = g * 32, n0 = j * 64;
    // stage whh slice once: coalesced global reads, XOR-swizzled LDS stores
    #pragma unroll
    for (int r = 0; r < 32; ++r) {
        int idx = r*256 + tid;
        int n = idx >> 7, kc = idx & 127;
        uint4 v = *(const uint4*)(whh + (size_t)(n0+n)*NOUT + kc*8);
        *(uint4*)(Bls + kc*1024 + (((n & 48) | ((n ^ kc) & 15))<<4)) = v;
    }
    int wm = wave >> 1, wn = wave & 1;
    int q = lane >> 4, ml = lane & 15;
    int na = wn*32 + ml, nb = wn*32 + 16 + ml;     // B-fragment col ids
    int ul = tid & 15;                              // epilogue unit-local
    float creg[2] = {0.f, 0.f};
    const unsigned short* hbuf[2] = {h0, h1};
    unsigned short* hbw[2] = {h0, h1};
    unsigned* dflags = bar + (size_t)(g * 64) * 16;
    __syncthreads();
    for (int t = 0; t < NN; ++t) {
        const unsigned short* h_in = hbuf[t & 1];
        const unsigned short* hrow = h_in + (size_t)(m0 + wm*16 + ml)*NOUT + q*8;
        f32x4 acc0 = (f32x4){0.f,0.f,0.f,0.f};
        f32x4 acc1 = (f32x4){0.f,0.f,0.f,0.f};
        #pragma unroll 8
        for (int it = 0; it < 32; ++it) {
            int kc = it*4 + q;
            bf16x8 a  = *(const bf16x8*)(hrow + it*32);
            bf16x8 b0 = *(const bf16x8*)(Bls + kc*1024 + (((na & 48) | ((na ^ kc) & 15))<<4));
            bf16x8 b1 = *(const bf16x8*)(Bls + kc*1024 + (((nb & 48) | ((nb ^ kc) & 15))<<4));
            acc0 = __builtin_amdgcn_mfma_f32_16x16x32_bf16(a, b0, acc0, 0, 0, 0);
            acc1 = __builtin_amdgcn_mfma_f32_16x16x32_bf16(a, b1, acc1, 0, 0, 0);
        }
        #pragma unroll
        for (int reg = 0; reg < 4; ++reg) {
            gates[wm*16 + q*4 + reg][wn*32 + ml]      = acc0[reg];
            gates[wm*16 + q*4 + reg][wn*32 + 16 + ml] = acc1[reg];
        }
        __syncthreads();
        // epilogue: 32 batches x 16 units = 512 pairs, 2/thread
        const unsigned short* xw_t = xw + (size_t)t*NB*4*NOUT;
        #pragma unroll
        for (int p = 0; p < 2; ++p) {
            int idx = p*256 + tid;
            int uli = idx & 15, bl = idx >> 4;
            int b = m0 + bl, u = j*16 + uli;
            float4 gl = *(const float4*)&gates[bl][uli*4];
            uint2 xw2 = *(const uint2*)(xw_t + (size_t)b*4*NOUT + n0 + uli*4);
            float g0 = gl.x + bf2f((unsigned short)(xw2.x & 0xffffu));
            float g1 = gl.y + bf2f((unsigned short)(xw2.x >> 16));
            float g2 = gl.z + bf2f((unsigned short)(xw2.y & 0xffffu));
            float g3 = gl.w + bf2f((unsigned short)(xw2.y >> 16));
            float ig = sigf(g0), fg = sigf(g1), gg = tanhf(g2), og = sigf(g3);
            float cc = fg*creg[p] + ig*gg;
            creg[p] = cc;
            if (t == NN-1) cout[(size_t)b*NOUT + u] = cc;
            else hbw[(t+1) & 1][(size_t)b*NOUT + u] = f2bf(og*tanhf(cc));
        }
        if (t < NN-1) {
            unsigned epoch = (unsigned)(t + 1);
            __syncthreads();   // all waves' h stores issued (vmcnt drain)
            if (tid == 0)
                __hip_atomic_store(dflags + (size_t)j*16, epoch,
                                   __ATOMIC_RELEASE, __HIP_MEMORY_SCOPE_AGENT);
            if (tid < 64) {    // one wave polls the domain's 64 flags
                while (__hip_atomic_load(dflags + (size_t)tid*16, __ATOMIC_RELAXED,
                                         __HIP_MEMORY_SCOPE_AGENT) < epoch)
                    __builtin_amdgcn_s_sleep(2);
            }
            __syncthreads();
            if (tid == 0)      // one acquire -> L2 invalidate, covers block
                (void)__hip_atomic_load(dflags, __ATOMIC_ACQUIRE, __HIP_MEMORY_SCOPE_AGENT);
            __syncthreads();
        }
    }
    (void)lane; (void)ul;
}

// ---------------------------------------------------------------------------
extern "C" void kernel_launch(void* const* d_in, const int* in_sizes, int n_in,
                              void* d_out, int out_size, void* d_ws, size_t ws_size,
                              hipStream_t stream) {
    (void)in_sizes; (void)n_in; (void)out_size; (void)ws_size;
    const float* boxes     = (const float*)d_in[0];
    const float* attention = (const float*)d_in[1];
    const float* features  = (const float*)d_in[2];
    const float* conv_w    = (const float*)d_in[3];
    const float* conv_b    = (const float*)d_in[4];
    const float* skew_wx   = (const float*)d_in[5];
    const float* skew_wy   = (const float*)d_in[6];
    const float* skew_b1   = (const float*)d_in[7];
    const float* skew_w2   = (const float*)d_in[8];
    // d_in[9] = skew_b2: cancels in C = out - out^T
    const float* w_ih      = (const float*)d_in[10];
    const float* w_hh      = (const float*)d_in[11];
    const float* b_ih      = (const float*)d_in[12];
    const float* b_hh      = (const float*)d_in[13];
    const float* lr        = (const float*)d_in[14];

    // workspace layout (bytes, 256-aligned). part (conv split-K partials)
    // and xw_bf share region 0 — partials dead before the xw GEMM writes.
    char* ws = (char*)d_ws;
    float*          part     = (float*)(ws);                      // 4x4608x512 f32  37,748,736
    unsigned short* xw_bf    = (unsigned short*)(ws);             // 4608x4096 bf16 (same region)
    unsigned short* features_bf = (unsigned short*)(ws + 37748736); // 18,874,368
    unsigned short* convw_bf = (unsigned short*)(ws + 56623104);  //  2,097,152
    float*          feats    = (float*)(ws + 58720256);           //  9,529,344
    float*          hxy      = (float*)(ws + 68249600);           //  4,718,592
    unsigned short* feats_bf = (unsigned short*)(ws + 72968192);  //  5,013,504
    unsigned short* xseq_bf  = (unsigned short*)(ws + 77981696);  //  5,013,504
    unsigned short* wih_il   = (unsigned short*)(ws + 82995200);  //  4,456,448
    unsigned short* whh_il   = (unsigned short*)(ws + 87451648);  //  8,388,608
    unsigned short* wxy_bf   = (unsigned short*)(ws + 95840256);  //    278,528
    float*          comb_b   = (float*)(ws + 96118784);           //     16,384
    float*          hxy_b    = (float*)(ws + 96135168);           //      1,024
    unsigned short* h0       = (unsigned short*)(ws + 96136192);  //    262,144
    unsigned short* h1       = (unsigned short*)(ws + 96398336);  //    262,144
    float*          out_g    = (float*)(ws + 96660480);           //    663,552
    float*          A_g      = (float*)(ws + 97324032);           //    663,552
    unsigned*       bar      = (unsigned*)(ws + 97987584);        //     16,448

    prep_all<<<2048, 256, 0, stream>>>(boxes, attention, features, conv_w,
                                       skew_wx, skew_wy, skew_b1, w_ih, w_hh,
                                       b_ih, b_hh, features_bf, convw_bf,
                                       wxy_bf, hxy_b, wih_il, whh_il, comb_b,
                                       h0, bar, feats);
    // conv split-K: 128x128 tiles, K-slice 512, grid (4,36,4) = 576 blocks
    gemm128<<<dim3(4, 36, 4), 256, 0, stream>>>(features_bf, convw_bf, nullptr,
                                                (void*)part, 512, NFEAT, NFEAT, 512, 0,
                                                (long long)ROWS*512);
    conv_reduce<<<2048, 256, 0, stream>>>(part, conv_b, feats, feats_bf);
    // hxy = feats . [wx;wy]^T + [b1;0]
    gemm_mfma<<<dim3(4, 36), 256, 0, stream>>>(feats_bf, wxy_bf, hxy_b,
                                               (void*)hxy, KP, KP, KP, 256, 0);
    // assignment pipeline
    out_k<<<dim3(NB, 4), 256, 0, stream>>>(hxy, skew_w2, out_g);
    iter_k<<<NB, 256, 0, stream>>>(out_g, attention, lr, A_g);
    xseq_k<<<dim3(NB, 2), 256, 0, stream>>>(feats, A_g, xseq_bf);
    // xw = xseq . w_ih_il^T + (b_ih+b_hh) -> bf16, 128x128 tiles, 1152 blocks
    gemm128<<<dim3(32, 36, 1), 256, 0, stream>>>(xseq_bf, wih_il, comb_b,
                                                 (void*)xw_bf, KP, KP, KP, 4*NOUT, 1, 0);
    // persistent LSTM, 4 independent 64-block domains, one dispatch
    lstm_domains<<<256, 256, 0, stream>>>(whh_il, xw_bf, h0, h1,
                                          (float*)d_out, bar);
}